// Round 9
// baseline (419.894 us; speedup 1.0000x reference)
//
#include <hip/hip_runtime.h>
#include <math.h>

#define K_CODES 512
#define DIM 64
#define NPTS (32 * 4096)   // 131072 points (B*HW)
#define NQ (NPTS * DIM)    // 8388608 quant_out elements
#define PPB 512            // points per block (2 per lane, 128 per wave)
#define SCODES 256         // codes staged per LDS half (64 KB)

// d_out layout (floats): [quant_out: 8388608][loss: 1][indices-as-float: 131072]

__global__ void init_kernel(float* __restrict__ loss) { loss[0] = 0.0f; }

// 256 blocks x 256 threads. Block stages the codebook through a 64KB LDS
// buffer in 2 halves; every wave scans all 512 codes for its own 128 points
// (2 per lane, x resident in VGPRs). Uniform-address ds_read_b128 broadcast,
// 8 FMAs per read -> VALU-bound. Ascending k + strict '>' = first-min ties.
__global__ __launch_bounds__(256, 1) void vq_kernel(const float* __restrict__ qin,
                                                    const float* __restrict__ cb,
                                                    float* __restrict__ out,
                                                    float* __restrict__ loss_acc,
                                                    float* __restrict__ idx_out) {
    __shared__ float stage[SCODES * DIM]; // 65536 B
    __shared__ float shalf[K_CODES];      // 2048 B
    __shared__ float wsum[4];

    int tid = threadIdx.x, lane = tid & 63, w = tid >> 6;

    // 0.5*||e_k||^2 table (2 codes per thread, from global)
    for (int kk = 0; kk < K_CODES; kk += 256) {
        int k = kk + tid;
        const float4* c4 = (const float4*)(cb + k * DIM);
        float s0 = 0.f, s1 = 0.f, s2 = 0.f, s3 = 0.f;
#pragma unroll
        for (int i = 0; i < 16; ++i) {
            float4 c = c4[i];
            s0 = fmaf(c.x, c.x, s0); s1 = fmaf(c.y, c.y, s1);
            s2 = fmaf(c.z, c.z, s2); s3 = fmaf(c.w, c.w, s3);
        }
        shalf[k] = 0.5f * ((s0 + s1) + (s2 + s3));
    }

    int L = blockIdx.x * PPB;     // block's first point
    int b = L >> 12;              // image index (512 | 4096, so single b)
    int hwb = L & 4095;
    int j0 = w * 128 + lane;      // local point a (this lane)
    // local point b = j0 + 64
    const float* base0 = qin + ((size_t)b << 18) + (hwb + j0);
    const float* base1 = base0 + 64;

    float x0[DIM], x1[DIM];
#pragma unroll
    for (int d = 0; d < DIM; ++d) {
        x0[d] = base0[(size_t)d << 12];
        x1[d] = base1[(size_t)d << 12];
    }

    const float4* cbv4 = (const float4*)cb;
    float4* stv4 = (float4*)stage;

    float bs0 = -INFINITY, bs1 = -INFINITY;
    int bi0 = 0, bi1 = 0;

    for (int half = 0; half < 2; ++half) {
        if (half) __syncthreads(); // all waves done reading previous half
        // cooperative stage: 256 codes = 4096 float4s, 16 per thread
        for (int j = 0; j < 16; ++j)
            stv4[j * 256 + tid] = cbv4[half * 4096 + j * 256 + tid];
        __syncthreads();           // stage (and shalf on first pass) ready

        int kb = half * SCODES;
        for (int kk = 0; kk < SCODES; ++kk) {
            const float4* sb = stv4 + kk * 16; // uniform -> LDS broadcast
            float a0 = 0.f, a1 = 0.f, a2 = 0.f, a3 = 0.f;
            float g0 = 0.f, g1 = 0.f, g2 = 0.f, g3 = 0.f;
#pragma unroll
            for (int i = 0; i < 16; ++i) {
                float4 cv = sb[i];
                a0 = fmaf(x0[4 * i + 0], cv.x, a0);
                a1 = fmaf(x0[4 * i + 1], cv.y, a1);
                a2 = fmaf(x0[4 * i + 2], cv.z, a2);
                a3 = fmaf(x0[4 * i + 3], cv.w, a3);
                g0 = fmaf(x1[4 * i + 0], cv.x, g0);
                g1 = fmaf(x1[4 * i + 1], cv.y, g1);
                g2 = fmaf(x1[4 * i + 2], cv.z, g2);
                g3 = fmaf(x1[4 * i + 3], cv.w, g3);
            }
            int k = kb + kk;
            float sh = shalf[k];
            float sc0 = ((a0 + a1) + (a2 + a3)) - sh;
            float sc1 = ((g0 + g1) + (g2 + g3)) - sh;
            if (sc0 > bs0) { bs0 = sc0; bi0 = k; } // strict: smallest k on ties
            if (sc1 > bs1) { bs1 = sc1; bi1 = k; }
        }
    }

    // indices (lane-contiguous within wave)
    idx_out[L + j0] = (float)bi0;
    idx_out[L + j0 + 64] = (float)bi1;

    // gather + store + loss; same thread<->point mapping so x0/x1 reused.
    const float* ra = cb + bi0 * DIM;
    const float* rb = cb + bi1 * DIM;
    float* ob = out + ((size_t)b << 18) + hwb;
    float l0 = 0.f, l1 = 0.f;
#pragma unroll
    for (int d = 0; d < DIM; ++d) {
        float va = ra[d], vb = rb[d];
        size_t o = (size_t)d << 12;
        ob[o + j0] = va;
        ob[o + j0 + 64] = vb;
        float ea = va - x0[d], eb = vb - x1[d];
        l0 = fmaf(ea, ea, l0);
        l1 = fmaf(eb, eb, l1);
    }
    float s = l0 + l1;

    // wave reduce then one atomic per block
#pragma unroll
    for (int off = 32; off > 0; off >>= 1) s += __shfl_down(s, off);
    if (lane == 0) wsum[w] = s;
    __syncthreads();
    if (tid == 0) atomicAdd(loss_acc, (wsum[0] + wsum[1]) + (wsum[2] + wsum[3]));
}

__global__ void finalize_kernel(float* __restrict__ loss) {
    loss[0] = 1.2f * loss[0] / 8388608.0f; // (1+BETA)*mean
}

extern "C" void kernel_launch(void* const* d_in, const int* in_sizes, int n_in,
                              void* d_out, int out_size, void* d_ws, size_t ws_size,
                              hipStream_t stream) {
    const float* qin = (const float*)d_in[0]; // (32,64,64,64) f32
    const float* cb = (const float*)d_in[1];  // (512,64) f32
    float* out = (float*)d_out;
    float* loss_out = out + NQ;
    float* idx_out = out + NQ + 1;

    init_kernel<<<1, 1, 0, stream>>>(loss_out);
    vq_kernel<<<NPTS / PPB, 256, 0, stream>>>(qin, cb, out, loss_out, idx_out);
    finalize_kernel<<<1, 1, 0, stream>>>(loss_out);
}

// Round 10
// 273.063 us; speedup vs baseline: 1.5377x; 1.5377x over previous
//
#include <hip/hip_runtime.h>
#include <math.h>

#define K_CODES 512
#define DIM 64
#define NPTS (32 * 4096)   // 131072 points
#define NQ (NPTS * DIM)    // 8388608 quant_out elements
#define BPTS 256           // points per block
#define ASTR 136           // f16 row stride (272B: 16B-aligned, 2-way banks on frag reads)
#define TAU 2.0e-3f        // rescue margin >> worst-case split-f16 error (~5.5e-4)

typedef _Float16 f16x8 __attribute__((ext_vector_type(8)));
typedef float f32x4 __attribute__((ext_vector_type(4)));

// d_out layout (floats): [quant_out: 8388608][loss: 1][indices-as-float: 131072]
// d_ws layout: [bp: 512*128 f16 = 131072B][shalf: 512 f32]

__global__ void init_kernel(float* __restrict__ loss) { loss[0] = 0.0f; }
__global__ void finalize_kernel(float* __restrict__ loss) {
    loss[0] = 1.2f * loss[0] / 8388608.0f; // (1+BETA)*mean
}

// Split codebook rows into f16 (hi,lo) pairs + 0.5*||e||^2 table.
__global__ __launch_bounds__(64) void prep_kernel(const float* __restrict__ cb,
                                                  _Float16* __restrict__ bp,
                                                  float* __restrict__ shalfg) {
    int k = blockIdx.x, d = threadIdx.x; // 512 blocks x 64 threads
    float e = cb[k * DIM + d];
    _Float16 hi = (_Float16)e;
    _Float16 lo = (_Float16)(e - (float)hi);
    bp[k * 128 + d] = hi;
    bp[k * 128 + 64 + d] = lo;
    float s = e * e;
#pragma unroll
    for (int m = 32; m; m >>= 1) s += __shfl_xor(s, m);
    if (d == 0) shalfg[k] = 0.5f * s;
}

// 512 blocks x 256 thr (4 waves). Block = 256 points; wave = 64 points.
// Virtual K=192 GEMM (hi*hi | lo*hi | hi*lo) vs all 512 codes via LDS tiles.
__global__ __launch_bounds__(256, 1) void vq_main(const float* __restrict__ qin,
                                                  const float* __restrict__ cb,
                                                  const _Float16* __restrict__ bp,
                                                  const float* __restrict__ shalfg,
                                                  float* __restrict__ out,
                                                  float* __restrict__ loss_acc,
                                                  float* __restrict__ idx_out) {
    __shared__ _Float16 Asm[BPTS][ASTR];  // [pt][hi(64)|lo(64)]
    __shared__ _Float16 Bsm[256][ASTR];   // half of codes, same layout
    __shared__ float shs[K_CODES];
    __shared__ int sfinal[BPTS];
    __shared__ float wsum[4];

    const int tid = threadIdx.x;
    const int lane = tid & 63;
    const int w = tid >> 6;
    const int row16 = lane & 15;
    const int kg = lane >> 4;
    const int wp = w * 64;

    const int n0 = blockIdx.x * BPTS;
    const int b = n0 >> 12;
    const int hw0 = n0 & 4095;
    const float* qbase = qin + ((size_t)b << 18) + hw0;

    shs[tid] = shalfg[tid];
    shs[tid + 256] = shalfg[tid + 256];

    // stage A: pt = tid, split into f16 pairs
    for (int d = 0; d < DIM; ++d) {
        float xv = qbase[((size_t)d << 12) + tid];
        _Float16 hi = (_Float16)xv;
        Asm[tid][d] = hi;
        Asm[tid][64 + d] = (_Float16)(xv - (float)hi);
    }

    float b1[16], b2[16];
    int k1[16];
#pragma unroll
    for (int sl = 0; sl < 16; ++sl) { b1[sl] = -INFINITY; b2[sl] = -INFINITY; k1[sl] = 0; }

    constexpr int mapA[6] = {0, 32, 64, 96, 0, 32};
    constexpr int mapB[6] = {0, 32, 0, 32, 64, 96};

    for (int h = 0; h < 2; ++h) {
        __syncthreads(); // A ready / previous half consumed
        // stage B half: 256 codes x 128 f16 (packed in bp) -> padded LDS
        const float4* src = (const float4*)(bp + (size_t)h * 256 * 128);
        for (int i = 0; i < 16; ++i) {
            int fidx = i * 256 + tid;
            int code = fidx >> 4, q = fidx & 15;
            float4 v = src[code * 16 + q];
            *(float4*)&Bsm[code][q * 8] = v;
        }
        __syncthreads();

        // hoist A-frags (4 row-frags x 6 k-chunks)
        f16x8 af[4][6];
#pragma unroll
        for (int rf = 0; rf < 4; ++rf)
#pragma unroll
            for (int c = 0; c < 6; ++c)
                af[rf][c] = *(const f16x8*)&Asm[wp + rf * 16 + row16][mapA[c] + kg * 8];

        for (int cf = 0; cf < 16; ++cf) {
            int codeL = cf * 16 + row16;
            f16x8 bf[6];
#pragma unroll
            for (int c = 0; c < 6; ++c)
                bf[c] = *(const f16x8*)&Bsm[codeL][mapB[c] + kg * 8];
            f32x4 ac0 = {0.f, 0.f, 0.f, 0.f}, ac1 = ac0, ac2 = ac0, ac3 = ac0;
#pragma unroll
            for (int c = 0; c < 6; ++c) {
                ac0 = __builtin_amdgcn_mfma_f32_16x16x32_f16(af[0][c], bf[c], ac0, 0, 0, 0);
                ac1 = __builtin_amdgcn_mfma_f32_16x16x32_f16(af[1][c], bf[c], ac1, 0, 0, 0);
                ac2 = __builtin_amdgcn_mfma_f32_16x16x32_f16(af[2][c], bf[c], ac2, 0, 0, 0);
                ac3 = __builtin_amdgcn_mfma_f32_16x16x32_f16(af[3][c], bf[c], ac3, 0, 0, 0);
            }
            int kglob = h * 256 + cf * 16 + row16;
            float sh = shs[kglob];
#define UPD(RF, AC)                                                       \
            {                                                             \
                _Pragma("unroll") for (int r = 0; r < 4; ++r) {           \
                    float s = (AC)[r] - sh;                               \
                    int sl = (RF) * 4 + r;                                \
                    bool c1 = s > b1[sl];                                 \
                    bool c2 = s > b2[sl];                                 \
                    b2[sl] = c1 ? b1[sl] : (c2 ? s : b2[sl]);             \
                    b1[sl] = c1 ? s : b1[sl];                             \
                    k1[sl] = c1 ? kglob : k1[sl];                         \
                }                                                         \
            }
            UPD(0, ac0) UPD(1, ac1) UPD(2, ac2) UPD(3, ac3)
#undef UPD
        }
    }

    // cross-lane reduce over the 16 lanes sharing the same kg (xor 1,2,4,8)
#pragma unroll
    for (int m = 1; m <= 8; m <<= 1) {
#pragma unroll
        for (int sl = 0; sl < 16; ++sl) {
            float ob1 = __shfl_xor(b1[sl], m);
            float ob2 = __shfl_xor(b2[sl], m);
            int ok1 = __shfl_xor(k1[sl], m);
            float nb2 = fmaxf(fminf(b1[sl], ob1), fmaxf(b2[sl], ob2));
            bool take = (ob1 > b1[sl]) || (ob1 == b1[sl] && ok1 < k1[sl]);
            b1[sl] = take ? ob1 : b1[sl];
            k1[sl] = take ? ok1 : k1[sl];
            b2[sl] = nb2;
        }
    }

    // owner lanes (row16==0) finalize their 16 points; rescue near-ties in f32
    if (row16 == 0) {
#pragma unroll 1
        for (int sl = 0; sl < 16; ++sl) {
            int pt = wp + (sl >> 2) * 16 + kg * 4 + (sl & 3);
            int kbest = k1[sl];
            if (b1[sl] - b2[sl] < TAU) {
                float x[DIM];
                const float* xb = qbase + pt;
#pragma unroll
                for (int d = 0; d < DIM; ++d) x[d] = xb[(size_t)d << 12];
                float bs = -INFINITY;
                int bi = 0;
                for (int k = 0; k < K_CODES; ++k) { // exact f32, r6 chain
                    const float4* c4 = (const float4*)(cb + (size_t)k * DIM);
                    float d0 = 0.f, d1 = 0.f, d2 = 0.f, d3 = 0.f;
#pragma unroll
                    for (int i = 0; i < 16; ++i) {
                        float4 c = c4[i];
                        d0 = fmaf(x[4 * i + 0], c.x, d0);
                        d1 = fmaf(x[4 * i + 1], c.y, d1);
                        d2 = fmaf(x[4 * i + 2], c.z, d2);
                        d3 = fmaf(x[4 * i + 3], c.w, d3);
                    }
                    float sc = ((d0 + d1) + (d2 + d3)) - shs[k];
                    if (sc > bs) { bs = sc; bi = k; }
                }
                kbest = bi;
            }
            sfinal[pt] = kbest;
            idx_out[n0 + pt] = (float)kbest;
        }
    }
    __syncthreads();

    // gather + store + loss (thread = point, f32 codebook => exact values)
    int ci = sfinal[tid];
    const float* crow = cb + (size_t)ci * DIM;
    float* obase = out + ((size_t)b << 18) + hw0;
    float l0 = 0.f, l1 = 0.f, l2 = 0.f, l3 = 0.f;
#pragma unroll
    for (int d = 0; d < DIM; d += 4) {
        float4 v = *(const float4*)(crow + d);
        obase[((size_t)(d + 0) << 12) + tid] = v.x;
        obase[((size_t)(d + 1) << 12) + tid] = v.y;
        obase[((size_t)(d + 2) << 12) + tid] = v.z;
        obase[((size_t)(d + 3) << 12) + tid] = v.w;
        float q0 = qbase[((size_t)(d + 0) << 12) + tid];
        float q1 = qbase[((size_t)(d + 1) << 12) + tid];
        float q2 = qbase[((size_t)(d + 2) << 12) + tid];
        float q3 = qbase[((size_t)(d + 3) << 12) + tid];
        float e0 = v.x - q0, e1 = v.y - q1, e2 = v.z - q2, e3 = v.w - q3;
        l0 = fmaf(e0, e0, l0); l1 = fmaf(e1, e1, l1);
        l2 = fmaf(e2, e2, l2); l3 = fmaf(e3, e3, l3);
    }
    float s = (l0 + l1) + (l2 + l3);
#pragma unroll
    for (int off = 32; off > 0; off >>= 1) s += __shfl_down(s, off);
    if (lane == 0) wsum[w] = s;
    __syncthreads();
    if (tid == 0) atomicAdd(loss_acc, (wsum[0] + wsum[1]) + (wsum[2] + wsum[3]));
}

extern "C" void kernel_launch(void* const* d_in, const int* in_sizes, int n_in,
                              void* d_out, int out_size, void* d_ws, size_t ws_size,
                              hipStream_t stream) {
    const float* qin = (const float*)d_in[0]; // (32,64,64,64) f32
    const float* cb = (const float*)d_in[1];  // (512,64) f32
    float* out = (float*)d_out;
    float* loss_out = out + NQ;
    float* idx_out = out + NQ + 1;

    _Float16* bp = (_Float16*)d_ws;                         // 131072 B
    float* shalfg = (float*)((char*)d_ws + 512 * 128 * 2);  // 2048 B

    init_kernel<<<1, 1, 0, stream>>>(loss_out);
    prep_kernel<<<K_CODES, 64, 0, stream>>>(cb, bp, shalfg);
    vq_main<<<NPTS / BPTS, 256, 0, stream>>>(qin, cb, bp, shalfg, out, loss_out, idx_out);
    finalize_kernel<<<1, 1, 0, stream>>>(loss_out);
}

// Round 11
// 247.000 us; speedup vs baseline: 1.7000x; 1.1055x over previous
//
#include <hip/hip_runtime.h>
#include <math.h>

#define K_CODES 512
#define DIM 64
#define NPTS (32 * 4096)   // 131072 points
#define NQ (NPTS * DIM)    // 8388608 quant_out elements
#define BPTS 256           // points per block
#define TAU 2.0e-3f        // rescue margin >> worst-case split-f16 error (~5.5e-4)

typedef _Float16 f16x8 __attribute__((ext_vector_type(8)));
typedef float f32x4 __attribute__((ext_vector_type(4)));

// d_out layout (floats): [quant_out: 8388608][loss: 1][indices-as-float: 131072]
// d_ws layout: [blob: 32cf*4q*64lane*8 f16 = 131072B][shalf: 512 f32]  (same 133120B as r10)

__global__ void init_kernel(float* __restrict__ loss) { loss[0] = 0.0f; }
__global__ void finalize_kernel(float* __restrict__ loss) {
    loss[0] = 1.2f * loss[0] / 8388608.0f; // (1+BETA)*mean
}

// Fragment-ready split-f16 codebook:
// frag f = cf*4 + q (q: 0=hi d0..31, 1=hi d32..63, 2=lo d0..31, 3=lo d32..63)
// lane l = kg*16+col holds elems j=0..7: bprow[cf*16+col][q-part, kg*8+j]
__global__ __launch_bounds__(64) void prep_kernel(const float* __restrict__ cb,
                                                  _Float16* __restrict__ blob,
                                                  float* __restrict__ shalfg) {
    int k = blockIdx.x, d = threadIdx.x; // 512 blocks x 64 threads
    float e = cb[k * DIM + d];
    _Float16 hi = (_Float16)e;
    _Float16 lo = (_Float16)(e - (float)hi);
    int cf = k >> 4, col = k & 15;
    int q = d >> 5, dd = d & 31, kg = dd >> 3, j = dd & 7;
    size_t base = ((size_t)(cf * 4 + q) * 64 + (kg * 16 + col)) * 8 + j;
    blob[base] = hi;
    blob[base + 2 * 64 * 8] = lo; // q+2 frag
    float s = e * e;
#pragma unroll
    for (int m = 32; m; m >>= 1) s += __shfl_xor(s, m);
    if (d == 0) shalfg[k] = 0.5f * s;
}

// 512 blocks x 256 thr (4 waves). Wave = 64 points, scans all 512 codes.
// B-frags streamed from L2-resident blob (no LDS); A-frags in registers.
// Virtual K=192: hi*hi + lo*hi + hi*lo, C-init = -0.5||e||^2.
__global__ __launch_bounds__(256, 1) void vq_main(const float* __restrict__ qin,
                                                  const float* __restrict__ cb,
                                                  const _Float16* __restrict__ blob,
                                                  const float* __restrict__ shalfg,
                                                  float* __restrict__ out,
                                                  float* __restrict__ loss_acc,
                                                  float* __restrict__ idx_out) {
    __shared__ int sfinal[BPTS];
    __shared__ float wsum[4];

    const int tid = threadIdx.x, lane = tid & 63, w = tid >> 6;
    const int row16 = lane & 15, kg = lane >> 4;
    const int wp = w * 64;
    const int n0 = blockIdx.x * BPTS;
    const int b = n0 >> 12, hw0 = n0 & 4095;
    const float* qbase = qin + ((size_t)b << 18) + hw0;
    const f16x8* bl = (const f16x8*)blob;

#pragma unroll 1
    for (int p = 0; p < 2; ++p) { // rf = 2p, 2p+1
        // ---- A-frags in registers (hi/lo split on the fly) ----
        f16x8 ah0[2], ah1[2], al0[2], al1[2];
#pragma unroll
        for (int rr = 0; rr < 2; ++rr) {
            const float* xb = qbase + (wp + (2 * p + rr) * 16 + row16);
#pragma unroll
            for (int j = 0; j < 8; ++j) {
                float xa = xb[(size_t)(kg * 8 + j) << 12];
                float xc = xb[(size_t)(32 + kg * 8 + j) << 12];
                _Float16 ha = (_Float16)xa, hc = (_Float16)xc;
                ah0[rr][j] = ha; al0[rr][j] = (_Float16)(xa - (float)ha);
                ah1[rr][j] = hc; al1[rr][j] = (_Float16)(xc - (float)hc);
            }
        }

        float b1[8], b2[8];
        int k1[8];
#pragma unroll
        for (int sl = 0; sl < 8; ++sl) { b1[sl] = -INFINITY; b2[sl] = -INFINITY; k1[sl] = 0; }

#pragma unroll 2
        for (int cf = 0; cf < 32; ++cf) {
            float sh = shalfg[cf * 16 + row16];
            f16x8 bh0 = bl[(cf * 4 + 0) * 64 + lane];
            f16x8 bh1 = bl[(cf * 4 + 1) * 64 + lane];
            f16x8 bl0 = bl[(cf * 4 + 2) * 64 + lane];
            f16x8 bl1 = bl[(cf * 4 + 3) * 64 + lane];
            f32x4 ini = {-sh, -sh, -sh, -sh};
            f32x4 ac0 = ini, ac1 = ini;
            ac0 = __builtin_amdgcn_mfma_f32_16x16x32_f16(ah0[0], bh0, ac0, 0, 0, 0);
            ac1 = __builtin_amdgcn_mfma_f32_16x16x32_f16(ah0[1], bh0, ac1, 0, 0, 0);
            ac0 = __builtin_amdgcn_mfma_f32_16x16x32_f16(ah1[0], bh1, ac0, 0, 0, 0);
            ac1 = __builtin_amdgcn_mfma_f32_16x16x32_f16(ah1[1], bh1, ac1, 0, 0, 0);
            ac0 = __builtin_amdgcn_mfma_f32_16x16x32_f16(al0[0], bh0, ac0, 0, 0, 0);
            ac1 = __builtin_amdgcn_mfma_f32_16x16x32_f16(al0[1], bh0, ac1, 0, 0, 0);
            ac0 = __builtin_amdgcn_mfma_f32_16x16x32_f16(al1[0], bh1, ac0, 0, 0, 0);
            ac1 = __builtin_amdgcn_mfma_f32_16x16x32_f16(al1[1], bh1, ac1, 0, 0, 0);
            ac0 = __builtin_amdgcn_mfma_f32_16x16x32_f16(ah0[0], bl0, ac0, 0, 0, 0);
            ac1 = __builtin_amdgcn_mfma_f32_16x16x32_f16(ah0[1], bl0, ac1, 0, 0, 0);
            ac0 = __builtin_amdgcn_mfma_f32_16x16x32_f16(ah1[0], bl1, ac0, 0, 0, 0);
            ac1 = __builtin_amdgcn_mfma_f32_16x16x32_f16(ah1[1], bl1, ac1, 0, 0, 0);
            int kglob = cf * 16 + row16;
#define UPD(RR, AC)                                               \
            {                                                     \
                _Pragma("unroll") for (int r = 0; r < 4; ++r) {   \
                    float s = (AC)[r];                            \
                    int sl = (RR) * 4 + r;                        \
                    bool c1 = s > b1[sl];                         \
                    bool c2 = s > b2[sl];                         \
                    b2[sl] = c1 ? b1[sl] : (c2 ? s : b2[sl]);     \
                    b1[sl] = c1 ? s : b1[sl];                     \
                    k1[sl] = c1 ? kglob : k1[sl];                 \
                }                                                 \
            }
            UPD(0, ac0) UPD(1, ac1)
#undef UPD
        }

        // reduce top-2 across the 16 col-lanes (xor 1,2,4,8); smallest k on ties
#pragma unroll
        for (int m = 1; m <= 8; m <<= 1) {
#pragma unroll
            for (int sl = 0; sl < 8; ++sl) {
                float ob1 = __shfl_xor(b1[sl], m);
                float ob2 = __shfl_xor(b2[sl], m);
                int ok1 = __shfl_xor(k1[sl], m);
                float nb2 = fmaxf(fminf(b1[sl], ob1), fmaxf(b2[sl], ob2));
                bool take = (ob1 > b1[sl]) || (ob1 == b1[sl] && ok1 < k1[sl]);
                b1[sl] = take ? ob1 : b1[sl];
                k1[sl] = take ? ok1 : k1[sl];
                b2[sl] = nb2;
            }
        }

        if (row16 == 0) { // owner lanes finalize 8 points; rescue near-ties in f32
#pragma unroll 1
            for (int sl = 0; sl < 8; ++sl) {
                int pt = wp + (2 * p + (sl >> 2)) * 16 + kg * 4 + (sl & 3);
                int kbest = k1[sl];
                if (b1[sl] - b2[sl] < TAU) {
                    float x[DIM];
                    const float* xb = qbase + pt;
#pragma unroll
                    for (int d = 0; d < DIM; ++d) x[d] = xb[(size_t)d << 12];
                    float bs = -INFINITY;
                    int bi = 0;
                    for (int k = 0; k < K_CODES; ++k) { // exact f32, r6 chain
                        const float4* c4 = (const float4*)(cb + (size_t)k * DIM);
                        float d0 = 0.f, d1 = 0.f, d2 = 0.f, d3 = 0.f;
#pragma unroll
                        for (int i = 0; i < 16; ++i) {
                            float4 c = c4[i];
                            d0 = fmaf(x[4 * i + 0], c.x, d0);
                            d1 = fmaf(x[4 * i + 1], c.y, d1);
                            d2 = fmaf(x[4 * i + 2], c.z, d2);
                            d3 = fmaf(x[4 * i + 3], c.w, d3);
                        }
                        float sc = ((d0 + d1) + (d2 + d3)) - shalfg[k];
                        if (sc > bs) { bs = sc; bi = k; }
                    }
                    kbest = bi;
                }
                sfinal[pt] = kbest;
                idx_out[n0 + pt] = (float)kbest;
            }
        }
    }
    __syncthreads();

    // gather + store + loss (thread = point, f32 codebook => exact values)
    int ci = sfinal[tid];
    const float* crow = cb + (size_t)ci * DIM;
    float* obase = out + ((size_t)b << 18) + hw0;
    float l0 = 0.f, l1 = 0.f, l2 = 0.f, l3 = 0.f;
#pragma unroll
    for (int d = 0; d < DIM; d += 4) {
        float4 v = *(const float4*)(crow + d);
        obase[((size_t)(d + 0) << 12) + tid] = v.x;
        obase[((size_t)(d + 1) << 12) + tid] = v.y;
        obase[((size_t)(d + 2) << 12) + tid] = v.z;
        obase[((size_t)(d + 3) << 12) + tid] = v.w;
        float q0 = qbase[((size_t)(d + 0) << 12) + tid];
        float q1 = qbase[((size_t)(d + 1) << 12) + tid];
        float q2 = qbase[((size_t)(d + 2) << 12) + tid];
        float q3 = qbase[((size_t)(d + 3) << 12) + tid];
        float e0 = v.x - q0, e1 = v.y - q1, e2 = v.z - q2, e3 = v.w - q3;
        l0 = fmaf(e0, e0, l0); l1 = fmaf(e1, e1, l1);
        l2 = fmaf(e2, e2, l2); l3 = fmaf(e3, e3, l3);
    }
    float s = (l0 + l1) + (l2 + l3);
#pragma unroll
    for (int off = 32; off > 0; off >>= 1) s += __shfl_down(s, off);
    if (lane == 0) wsum[w] = s;
    __syncthreads();
    if (tid == 0) atomicAdd(loss_acc, (wsum[0] + wsum[1]) + (wsum[2] + wsum[3]));
}

extern "C" void kernel_launch(void* const* d_in, const int* in_sizes, int n_in,
                              void* d_out, int out_size, void* d_ws, size_t ws_size,
                              hipStream_t stream) {
    const float* qin = (const float*)d_in[0]; // (32,64,64,64) f32
    const float* cb = (const float*)d_in[1];  // (512,64) f32
    float* out = (float*)d_out;
    float* loss_out = out + NQ;
    float* idx_out = out + NQ + 1;

    _Float16* blob = (_Float16*)d_ws;                       // 131072 B
    float* shalfg = (float*)((char*)d_ws + 512 * 128 * 2);  // 2048 B

    init_kernel<<<1, 1, 0, stream>>>(loss_out);
    prep_kernel<<<K_CODES, 64, 0, stream>>>(cb, blob, shalfg);
    vq_main<<<NPTS / BPTS, 256, 0, stream>>>(qin, cb, blob, shalfg, out, loss_out, idx_out);
    finalize_kernel<<<1, 1, 0, stream>>>(loss_out);
}